// Round 10
// baseline (3620.853 us; speedup 1.0000x reference)
//
#include <hip/hip_runtime.h>
#include <hip/hip_bf16.h>

#define VOCAB 4096
#define BB 4
#define LL 2048
#define SEG 16
#define SEGL 128  // LL/SEG

typedef __hip_bfloat16 bf16;
typedef __bf16 bf16x8 __attribute__((ext_vector_type(8)));
typedef float f32x4 __attribute__((ext_vector_type(4)));

__device__ __forceinline__ void gload16(const void* g, void* l) {
  __builtin_amdgcn_global_load_lds(
      (const __attribute__((address_space(1))) unsigned int*)g,
      (__attribute__((address_space(3))) unsigned int*)l, 16, 0, 0);
}

__device__ __forceinline__ bf16x8 as_bf(f32x4 v) {
  union { f32x4 f; bf16x8 b; } u;
  u.f = v;
  return u.b;
}

// ---------------- transpose f32 [K][N] -> bf16 [N][K] ----------------
__global__ void transpose_f32_bf16(const float* __restrict__ in,
                                   bf16* __restrict__ out, int K, int N) {
  __shared__ float tile[32][33];
  int bx = blockIdx.x;  // tile along N
  int by = blockIdx.y;  // tile along K
  int x = bx * 32 + threadIdx.x;
#pragma unroll
  for (int i = threadIdx.y; i < 32; i += 8)
    tile[i][threadIdx.x] = in[(size_t)(by * 32 + i) * N + x];
  __syncthreads();
  int k = by * 32 + threadIdx.x;
#pragma unroll
  for (int i = threadIdx.y; i < 32; i += 8)
    out[(size_t)(bx * 32 + i) * K + k] = __float2bfloat16(tile[threadIdx.x][i]);
}

// -------- ctx pass A: per-segment sigmoid column sums --------
__global__ void ctx_partial(const int* __restrict__ idx,
                            const float* __restrict__ Mlog,
                            float* __restrict__ segsum) {
  int b = blockIdx.x / (16 * SEG);
  int rem = blockIdx.x % (16 * SEG);
  int chunk = rem / SEG;
  int s = rem % SEG;
  int col = chunk * 256 + threadIdx.x;
  __shared__ int sidx[SEGL];
  if (threadIdx.x < SEGL)
    sidx[threadIdx.x] = idx[b * LL + s * SEGL + threadIdx.x];
  __syncthreads();
  const float* base = Mlog + col;
  float a0 = 0.f, a1 = 0.f, a2 = 0.f, a3 = 0.f;
#pragma unroll 4
  for (int t = 0; t < SEGL; t += 4) {
    float v0 = base[(size_t)sidx[t + 0] * VOCAB];
    float v1 = base[(size_t)sidx[t + 1] * VOCAB];
    float v2 = base[(size_t)sidx[t + 2] * VOCAB];
    float v3 = base[(size_t)sidx[t + 3] * VOCAB];
    a0 += 1.f / (1.f + __expf(-v0));
    a1 += 1.f / (1.f + __expf(-v1));
    a2 += 1.f / (1.f + __expf(-v2));
    a3 += 1.f / (1.f + __expf(-v3));
  }
  segsum[(size_t)blockIdx.x * 256 + threadIdx.x] = (a0 + a1) + (a2 + a3);
}

// -------- ctx pass B: replay segment with offset, write running mean --------
__global__ void ctx_final(const int* __restrict__ idx,
                          const float* __restrict__ Mlog,
                          const float* __restrict__ segsum,
                          bf16* __restrict__ ctx) {
  int b = blockIdx.x / (16 * SEG);
  int rem = blockIdx.x % (16 * SEG);
  int chunk = rem / SEG;
  int s = rem % SEG;
  int col = chunk * 256 + threadIdx.x;
  __shared__ int sidx[SEGL];
  if (threadIdx.x < SEGL)
    sidx[threadIdx.x] = idx[b * LL + s * SEGL + threadIdx.x];
  __syncthreads();
  const float* ss = segsum + (size_t)((b * 16 + chunk) * SEG) * 256 + threadIdx.x;
  float acc = 0.f;
  for (int s2 = 0; s2 < s; ++s2) acc += ss[(size_t)s2 * 256];
  const float* base = Mlog + col;
  bf16* outp = ctx + ((size_t)b * LL + (size_t)s * SEGL) * VOCAB + col;
#pragma unroll 8
  for (int t = 0; t < SEGL; ++t) {
    float v = base[(size_t)sidx[t] * VOCAB];
    acc += 1.f / (1.f + __expf(-v));
    float inv = __fdividef(1.f, (float)(s * SEGL + t + 1));
    outp[(size_t)t * VOCAB] = __float2bfloat16(acc * inv);
  }
}

// ------- 256x256 bf16 GEMM — 4-wave (1/SIMD) conservative 1-phase ---------
// Round-9 post-mortem: 4-wave substrate verified by hand; the cross-tile
// register skew NaN'd. This kernel keeps the substrate (128 read-instrs/tile
// vs 192 at 8 waves; MFMA floor 2483 cyc/tile now binding) under the PROVEN
// round-8 sync discipline, one phase per tile:
//   STG_TILE(t+1 -> ~p)            (16 gloads, issue-early: DMA covered by
//   32 ds_reads of buf p            reads + 128 MFMA >> 900cyc HBM)
//   LGKM0 + sched_barrier           (rule #18)
//   128 MFMA
//   VMW(0); BAR                     (single barrier/tile)
// Hazards: RAW stage->read: VMW(0)+BAR at end of staging tile. WAR
// read->stage: reads drained by LGKM0 before that BAR; next stage into p is
// one tile later. No cross-tile register carrying; no partial vmcnt.
// acc[8][8] f32x4 = 256 AGPR; frags Ac 64 + Bq/Br 64 = 128 VGPR; fits the
// 512-reg unified budget at 1 wave/SIMD ((256,1) launch bounds).
// EPI==0: out = bf16 gelu_exact(C)   EPI==1: out = f32 C

#define BAR() asm volatile("s_barrier" ::: "memory")
#define LGKM0() asm volatile("s_waitcnt lgkmcnt(0)" ::: "memory")
#define VMW(n_) asm volatile("s_waitcnt vmcnt(" #n_ ")" ::: "memory")
#define SB0() __builtin_amdgcn_sched_barrier(0)
#define P1() __builtin_amdgcn_s_setprio(1)
#define P0() __builtin_amdgcn_s_setprio(0)

// stage a whole 256x64 K-tile (A then B) into buffer b_; 16 gload16/wave;
// slot q = tid + s*256 -> row = r0 + 32s, kc = kc0 (chunk-XOR layout)
#define STG_TILE(T_, b_)                                                  \
  _Pragma("unroll") for (int s_ = 0; s_ < 4; ++s_) {                      \
    const size_t ko_ = (size_t)(T_)*64;                                   \
    gload16(Asrc + (size_t)(32 * s_) * K + ko_,                           \
            sm + (b_)*32768 + s_ * 2048 + wave * 512);                    \
    gload16(Asrc + (size_t)(128 + 32 * s_) * K + ko_,                     \
            sm + (b_)*32768 + 8192 + s_ * 2048 + wave * 512);             \
    gload16(Bsrc + (size_t)(32 * s_) * K + ko_,                           \
            sm + (b_)*32768 + 16384 + s_ * 2048 + wave * 512);            \
    gload16(Bsrc + (size_t)(128 + 32 * s_) * K + ko_,                     \
            sm + (b_)*32768 + 24576 + s_ * 2048 + wave * 512);            \
  }

// one asm LDS read: 16B into f32x4, literal byte offset
#define RD1(dst_, base_, off_)                       \
  asm volatile("ds_read_b128 %0, %1 offset:%2"       \
               : "=v"(dst_)                          \
               : "v"(base_), "i"(off_)               \
               : "memory")

// full A (8 m-frags x 2 k-chunks) from buffer bases a0_/a1_
#define RD_AF(a0_, a1_)            \
  RD1(Ac[0][0], a0_, 0);           \
  RD1(Ac[0][1], a1_, 0);           \
  RD1(Ac[1][0], a0_, 2048);        \
  RD1(Ac[1][1], a1_, 2048);        \
  RD1(Ac[2][0], a0_, 4096);        \
  RD1(Ac[2][1], a1_, 4096);        \
  RD1(Ac[3][0], a0_, 6144);        \
  RD1(Ac[3][1], a1_, 6144);        \
  RD1(Ac[4][0], a0_, 8192);        \
  RD1(Ac[4][1], a1_, 8192);        \
  RD1(Ac[5][0], a0_, 10240);       \
  RD1(Ac[5][1], a1_, 10240);       \
  RD1(Ac[6][0], a0_, 12288);       \
  RD1(Ac[6][1], a1_, 12288);       \
  RD1(Ac[7][0], a0_, 14336);       \
  RD1(Ac[7][1], a1_, 14336);

// B quad (4 n-frags x 2 k); jb_ = 0 (cols 0-63) or 4 (cols 64-127)
#define RD_B4(dst_, b0_, b1_, jb_)              \
  RD1(dst_[0][0], b0_, ((jb_) + 0) * 2048);     \
  RD1(dst_[0][1], b1_, ((jb_) + 0) * 2048);     \
  RD1(dst_[1][0], b0_, ((jb_) + 1) * 2048);     \
  RD1(dst_[1][1], b1_, ((jb_) + 1) * 2048);     \
  RD1(dst_[2][0], b0_, ((jb_) + 2) * 2048);     \
  RD1(dst_[2][1], b1_, ((jb_) + 2) * 2048);     \
  RD1(dst_[3][0], b0_, ((jb_) + 3) * 2048);     \
  RD1(dst_[3][1], b1_, ((jb_) + 3) * 2048);

// 64 MFMA: acc[m][nb+j] += A x B over both k-chunks
#define MQ4(nb_, Bs_)                                                       \
  _Pragma("unroll") for (int m_ = 0; m_ < 8; ++m_)                          \
      _Pragma("unroll") for (int j_ = 0; j_ < 4; ++j_) {                    \
    f32x4& c_ = acc[m_][(nb_) + j_];                                        \
    c_ = __builtin_amdgcn_mfma_f32_16x16x32_bf16(as_bf(Ac[m_][0]),          \
                                                 as_bf(Bs_[j_][0]), c_, 0,  \
                                                 0, 0);                     \
    c_ = __builtin_amdgcn_mfma_f32_16x16x32_bf16(as_bf(Ac[m_][1]),          \
                                                 as_bf(Bs_[j_][1]), c_, 0,  \
                                                 0, 0);                     \
  }

// one K-tile, conservative: stage-early, read-all, wait, compute, drain, BAR
#define TILE_BODY(T_, p_, aK0_, aK1_, bK0_, bK1_)   \
  {                                                 \
    if ((T_) + 1 < NT) STG_TILE((T_) + 1, (p_) ^ 1);\
    RD_AF(aK0_, aK1_);                              \
    RD_B4(Bq, bK0_, bK1_, 0);                       \
    RD_B4(Br, bK0_, bK1_, 4);                       \
    LGKM0();                                        \
    SB0();                                          \
    P1();                                           \
    MQ4(0, Bq);                                     \
    MQ4(4, Br);                                     \
    P0();                                           \
    VMW(0);                                         \
    BAR();                                          \
  }

template <int EPI>
__global__ __launch_bounds__(256, 1) void gemm256(const bf16* __restrict__ A,
                                                  const bf16* __restrict__ Bt,
                                                  const float* __restrict__ bias,
                                                  void* __restrict__ outv,
                                                  int M, int N, int K) {
  __shared__ __align__(16) bf16 sm[65536];  // 128 KiB: 2 x (A 32KB | B 32KB)
  const int tid = threadIdx.x;
  const int wave = tid >> 6;
  const int lane = tid & 63;
  const int nwg = gridDim.x;
  const int bid = blockIdx.x;
  const int swz = (bid & 7) * (nwg >> 3) + (bid >> 3);  // nwg % 8 == 0
  const int gn = N >> 8;
  const int bm0 = (swz / gn) << 8;
  const int bn0 = (swz % gn) << 8;
  const int wm = (wave >> 1) << 7;  // wave m-offset: 0 or 128
  const int wn = (wave & 1) << 7;   // wave n-offset: 0 or 128
  const int rsel = lane & 15;
  const int ksel = lane >> 4;
  const int xorv = rsel & 7;

  // staging source: slot q = tid + s*256 -> row = r0+32s, kc = kc0
  const int r0 = tid >> 3;
  const int kc0 = (tid & 7) ^ (r0 & 7);
  const bf16* Asrc = A + (size_t)(bm0 + r0) * K + kc0 * 8;
  const bf16* Bsrc = Bt + (size_t)(bn0 + r0) * K + kc0 * 8;
  const int NT = K >> 6;

  // 32-bit LDS byte bases for asm ds_read (chunk-XOR folded in)
  const unsigned smbase =
      (unsigned)(unsigned long long)(__attribute__((address_space(3)))
                                     bf16*)sm;
  const unsigned kT0 = (unsigned)((ksel ^ xorv) << 4);
  const unsigned kT1 = (unsigned)(((ksel + 4) ^ xorv) << 4);
  const unsigned aRow = (unsigned)((wm + rsel) * 128);
  const unsigned bRow = (unsigned)((wn + rsel) * 128);
  const unsigned a00 = smbase + aRow + kT0;
  const unsigned a10 = smbase + aRow + kT1;
  const unsigned b00 = smbase + 32768u + bRow + kT0;
  const unsigned b10 = smbase + 32768u + bRow + kT1;
  const unsigned a01 = a00 + 65536u, a11 = a10 + 65536u;
  const unsigned b01 = b00 + 65536u, b11 = b10 + 65536u;

  f32x4 acc[8][8];
#pragma unroll
  for (int i = 0; i < 8; ++i)
#pragma unroll
    for (int j = 0; j < 8; ++j) acc[i][j] = (f32x4){0.f, 0.f, 0.f, 0.f};

  f32x4 Ac[8][2], Bq[4][2], Br[4][2];

  // prologue: stage tile0 -> buf0, full drain + barrier
  STG_TILE(0, 0);
  VMW(0);
  BAR();

  for (int t = 0; t < NT; t += 2) {
    TILE_BODY(t, 0, a00, a10, b00, b10);
    TILE_BODY(t + 1, 1, a01, a11, b01, b11);
  }

  // epilogue; C/D layout: col = lane&15, row = (lane>>4)*4 + reg
  const int cl = lane & 15;
  const int rg = lane >> 4;
#pragma unroll
  for (int m = 0; m < 8; ++m) {
    int grow = bm0 + wm + m * 16 + rg * 4;
#pragma unroll
    for (int n = 0; n < 8; ++n) {
      int col = bn0 + wn + n * 16 + cl;
      float bv = bias[col];
#pragma unroll
      for (int r = 0; r < 4; ++r) {
        size_t o = (size_t)(grow + r) * N + col;
        float v = acc[m][n][r] + bv;
        if (EPI == 0) {
          float g = 0.5f * v * (1.f + erff(v * 0.70710678118654752f));
          ((bf16*)outv)[o] = __float2bfloat16(g);
        } else {
          ((float*)outv)[o] = v;
        }
      }
    }
  }
}

extern "C" void kernel_launch(void* const* d_in, const int* in_sizes, int n_in,
                              void* d_out, int out_size, void* d_ws,
                              size_t ws_size, hipStream_t stream) {
  const int* idx = (const int*)d_in[0];       // [B,L]
  const float* Mlog = (const float*)d_in[1];  // [V,V]
  const float* W1 = (const float*)d_in[2];    // [V,2V]
  const float* b1 = (const float*)d_in[3];    // [2V]
  const float* W2 = (const float*)d_in[4];    // [2V,V]
  const float* b2 = (const float*)d_in[5];    // [V]
  float* out = (float*)d_out;                 // [B,L,V] f32

  char* ws = (char*)d_ws;
  const size_t MB64 = 64ull << 20;
  bf16* ctx = (bf16*)ws;             // 64 MiB  [8192][4096] (dead after GEMM1)
  bf16* W2t = (bf16*)ws;             // aliases ctx: [4096][8192]
  bf16* W1t = (bf16*)(ws + MB64);    // 64 MiB  [8192][4096]
  bf16* h = (bf16*)(ws + 2 * MB64);  // 128 MiB [8192][8192]
  float* segsum = (float*)h;         // 1 MiB, dead before GEMM1 writes h
  (void)ws_size;

  dim3 tb(32, 8);
  // W1^T cast
  transpose_f32_bf16<<<dim3(8192 / 32, 4096 / 32), tb, 0, stream>>>(W1, W1t,
                                                                    4096, 8192);
  // ctx = causal-mean(sigmoid(M)[idx]), segment-parallel two-pass
  ctx_partial<<<BB * 16 * SEG, 256, 0, stream>>>(idx, Mlog, segsum);
  ctx_final<<<BB * 16 * SEG, 256, 0, stream>>>(idx, Mlog, segsum, ctx);
  // h = gelu(ctx @ W1 + b1)  -> bf16
  gemm256<0><<<(8192 / 256) * (8192 / 256), 256, 0, stream>>>(
      ctx, W1t, b1, h, 8192, 8192, 4096);
  // W2^T cast (reuses ctx space)
  transpose_f32_bf16<<<dim3(4096 / 32, 8192 / 32), tb, 0, stream>>>(W2, W2t,
                                                                    8192, 4096);
  // out = h @ W2 + b2  -> f32
  gemm256<1><<<(8192 / 256) * (4096 / 256), 256, 0, stream>>>(
      h, W2t, b2, out, 8192, 4096, 8192);
}

// Round 11
// 1213.168 us; speedup vs baseline: 2.9846x; 2.9846x over previous
//
#include <hip/hip_runtime.h>
#include <hip/hip_bf16.h>

#define VOCAB 4096
#define BB 4
#define LL 2048
#define SEG 16
#define SEGL 128  // LL/SEG

typedef __hip_bfloat16 bf16;
typedef __bf16 bf16x8 __attribute__((ext_vector_type(8)));
typedef float f32x4 __attribute__((ext_vector_type(4)));
typedef float f32x16 __attribute__((ext_vector_type(16)));

__device__ __forceinline__ void gload16(const void* g, void* l) {
  __builtin_amdgcn_global_load_lds(
      (const __attribute__((address_space(1))) unsigned int*)g,
      (__attribute__((address_space(3))) unsigned int*)l, 16, 0, 0);
}

__device__ __forceinline__ bf16x8 as_bf(f32x4 v) {
  union { f32x4 f; bf16x8 b; } u;
  u.f = v;
  return u.b;
}

// ---------------- transpose f32 [K][N] -> bf16 [N][K] ----------------
__global__ void transpose_f32_bf16(const float* __restrict__ in,
                                   bf16* __restrict__ out, int K, int N) {
  __shared__ float tile[32][33];
  int bx = blockIdx.x;  // tile along N
  int by = blockIdx.y;  // tile along K
  int x = bx * 32 + threadIdx.x;
#pragma unroll
  for (int i = threadIdx.y; i < 32; i += 8)
    tile[i][threadIdx.x] = in[(size_t)(by * 32 + i) * N + x];
  __syncthreads();
  int k = by * 32 + threadIdx.x;
#pragma unroll
  for (int i = threadIdx.y; i < 32; i += 8)
    out[(size_t)(bx * 32 + i) * K + k] = __float2bfloat16(tile[threadIdx.x][i]);
}

// -------- ctx pass A: per-segment sigmoid column sums --------
__global__ void ctx_partial(const int* __restrict__ idx,
                            const float* __restrict__ Mlog,
                            float* __restrict__ segsum) {
  int b = blockIdx.x / (16 * SEG);
  int rem = blockIdx.x % (16 * SEG);
  int chunk = rem / SEG;
  int s = rem % SEG;
  int col = chunk * 256 + threadIdx.x;
  __shared__ int sidx[SEGL];
  if (threadIdx.x < SEGL)
    sidx[threadIdx.x] = idx[b * LL + s * SEGL + threadIdx.x];
  __syncthreads();
  const float* base = Mlog + col;
  float a0 = 0.f, a1 = 0.f, a2 = 0.f, a3 = 0.f;
#pragma unroll 4
  for (int t = 0; t < SEGL; t += 4) {
    float v0 = base[(size_t)sidx[t + 0] * VOCAB];
    float v1 = base[(size_t)sidx[t + 1] * VOCAB];
    float v2 = base[(size_t)sidx[t + 2] * VOCAB];
    float v3 = base[(size_t)sidx[t + 3] * VOCAB];
    a0 += 1.f / (1.f + __expf(-v0));
    a1 += 1.f / (1.f + __expf(-v1));
    a2 += 1.f / (1.f + __expf(-v2));
    a3 += 1.f / (1.f + __expf(-v3));
  }
  segsum[(size_t)blockIdx.x * 256 + threadIdx.x] = (a0 + a1) + (a2 + a3);
}

// -------- ctx pass B: replay segment with offset, write running mean --------
__global__ void ctx_final(const int* __restrict__ idx,
                          const float* __restrict__ Mlog,
                          const float* __restrict__ segsum,
                          bf16* __restrict__ ctx) {
  int b = blockIdx.x / (16 * SEG);
  int rem = blockIdx.x % (16 * SEG);
  int chunk = rem / SEG;
  int s = rem % SEG;
  int col = chunk * 256 + threadIdx.x;
  __shared__ int sidx[SEGL];
  if (threadIdx.x < SEGL)
    sidx[threadIdx.x] = idx[b * LL + s * SEGL + threadIdx.x];
  __syncthreads();
  const float* ss = segsum + (size_t)((b * 16 + chunk) * SEG) * 256 + threadIdx.x;
  float acc = 0.f;
  for (int s2 = 0; s2 < s; ++s2) acc += ss[(size_t)s2 * 256];
  const float* base = Mlog + col;
  bf16* outp = ctx + ((size_t)b * LL + (size_t)s * SEGL) * VOCAB + col;
#pragma unroll 8
  for (int t = 0; t < SEGL; ++t) {
    float v = base[(size_t)sidx[t] * VOCAB];
    acc += 1.f / (1.f + __expf(-v));
    float inv = __fdividef(1.f, (float)(s * SEGL + t + 1));
    outp[(size_t)t * VOCAB] = __float2bfloat16(acc * inv);
  }
}

// ------ 256x256 bf16 GEMM — round-8 skeleton, 32x32x16 MFMA, 2 phases -----
// 512 thr (2x4 waves), BK=64, 128KiB LDS dbuf, chunk-XOR swizzle, asm
// ds_read_b128, 2 barriers/tile (r8-proven). Changes vs r8: (1) MFMA
// 32x32x16 (m119: 2495 vs 2176 TF; 16 ops/phase of 2x the work -> MFMA run
// ~1030 cyc/SIMD dwarfs the lgkm wait); (2) phases merged 4->2 (2 lgkm
// windows/tile). Per tile: ph1 {rd B-all(8)+A-h0(8); stg A(t+1,h1)+B(t+1,h0)
// -> ~p; LGKM0+SB0; 16 MFMA}, mid-BAR, ph2 {rd A-h1(8); stg A(t+2,h0)+
// B(t+2,h1) -> p; LGKM0+SB0; 16 MFMA}. VMW(4) steady / VMW(0) last tile at
// tile top (FIFO: 12 outstanding, first 8 = tile t's halves).
// 32x32x16 layouts: A/B k = 8*(lane>>5)+j (same contiguous-8 pattern as the
// verified 16x16x32); C/D col=lane&31, row=(reg&3)+8*(reg>>2)+4*(lane>>5)
// [m74/m101 HW-verified]. EPI==0: bf16 gelu_exact(C); EPI==1: f32 C.

#define BAR() asm volatile("s_barrier" ::: "memory")
#define LGKM0() asm volatile("s_waitcnt lgkmcnt(0)" ::: "memory")
#define VMW(n_) asm volatile("s_waitcnt vmcnt(" #n_ ")" ::: "memory")
#define SB0() __builtin_amdgcn_sched_barrier(0)
#define P1() __builtin_amdgcn_s_setprio(1)
#define P0() __builtin_amdgcn_s_setprio(0)

#define STG_A(t_, h_, b_)                                           \
  {                                                                 \
    const bf16* s_ = Asrc + (size_t)(h_)*128 * K + (size_t)(t_)*64; \
    bf16* d_ = sm + (b_)*32768 + (h_)*8192 + wave * 512;            \
    gload16(s_, d_);                                                \
    gload16(s_ + rowK64, d_ + 4096);                                \
  }
#define STG_B(t_, h_, b_)                                           \
  {                                                                 \
    const bf16* s_ = Bsrc + (size_t)(h_)*128 * K + (size_t)(t_)*64; \
    bf16* d_ = sm + (b_)*32768 + 16384 + (h_)*8192 + wave * 512;    \
    gload16(s_, d_);                                                \
    gload16(s_ + rowK64, d_ + 4096);                                \
  }

// one asm LDS read: 16B into f32x4, literal byte offset
#define RD1(dst_, base_, off_)                       \
  asm volatile("ds_read_b128 %0, %1 offset:%2"       \
               : "=v"(dst_)                          \
               : "v"(base_), "i"(off_)               \
               : "memory")

// A phase mh_: 2 m-blocks x 4 ks from per-ks bases (buf-specific)
#define RD_A_PH(k0_, k1_, k2_, k3_, mh_)          \
  RD1(AcR[0][0], k0_, (mh_)*16384 + 0);           \
  RD1(AcR[0][1], k1_, (mh_)*16384 + 0);           \
  RD1(AcR[0][2], k2_, (mh_)*16384 + 0);           \
  RD1(AcR[0][3], k3_, (mh_)*16384 + 0);           \
  RD1(AcR[1][0], k0_, (mh_)*16384 + 4096);        \
  RD1(AcR[1][1], k1_, (mh_)*16384 + 4096);        \
  RD1(AcR[1][2], k2_, (mh_)*16384 + 4096);        \
  RD1(AcR[1][3], k3_, (mh_)*16384 + 4096);

// B all: 2 n-blocks (nh*16384) x 4 ks
#define RD_B_ALL(k0_, k1_, k2_, k3_)              \
  RD1(BcR[0][0], k0_, 0);                         \
  RD1(BcR[0][1], k1_, 0);                         \
  RD1(BcR[0][2], k2_, 0);                         \
  RD1(BcR[0][3], k3_, 0);                         \
  RD1(BcR[1][0], k0_, 16384);                     \
  RD1(BcR[1][1], k1_, 16384);                     \
  RD1(BcR[1][2], k2_, 16384);                     \
  RD1(BcR[1][3], k3_, 16384);

// 16 MFMA (32x32x16): ks-outer so consecutive ops hit different acc tiles
#define MQ32(mh_)                                                         \
  _Pragma("unroll") for (int ks_ = 0; ks_ < 4; ++ks_)                     \
      _Pragma("unroll") for (int mb_ = 0; mb_ < 2; ++mb_)                 \
          _Pragma("unroll") for (int nh_ = 0; nh_ < 2; ++nh_) {           \
    f32x16& c_ = acc[(mh_)*2 + mb_][nh_];                                 \
    c_ = __builtin_amdgcn_mfma_f32_32x32x16_bf16(                         \
        as_bf(AcR[mb_][ks_]), as_bf(BcR[nh_][ks_]), c_, 0, 0, 0);         \
  }

#define TILE_BODY(T_, p_, ak0_, ak1_, ak2_, ak3_, bk0_, bk1_, bk2_, bk3_) \
  {                                                                       \
    if ((T_) + 1 < NT) { VMW(4); } else { VMW(0); }                       \
    BAR();                                                                \
    /* ph1: rd B-all + A-h0 ; stg A(t+1,h1),B(t+1,h0) -> ~p ; MFMA */     \
    RD_B_ALL(bk0_, bk1_, bk2_, bk3_);                                     \
    RD_A_PH(ak0_, ak1_, ak2_, ak3_, 0);                                   \
    if ((T_) + 1 < NT) {                                                  \
      STG_A((T_) + 1, 1, (p_) ^ 1);                                       \
      STG_B((T_) + 1, 0, (p_) ^ 1);                                       \
    }                                                                     \
    LGKM0();                                                              \
    SB0();                                                                \
    P1(); MQ32(0); P0();                                                  \
    BAR();                                                                \
    /* ph2: rd A-h1 ; stg A(t+2,h0),B(t+2,h1) -> p ; MFMA */              \
    RD_A_PH(ak0_, ak1_, ak2_, ak3_, 1);                                   \
    if ((T_) + 2 < NT) {                                                  \
      STG_A((T_) + 2, 0, (p_));                                           \
      STG_B((T_) + 2, 1, (p_));                                           \
    }                                                                     \
    LGKM0();                                                              \
    SB0();                                                                \
    P1(); MQ32(1); P0();                                                  \
  }

template <int EPI>
__global__ __launch_bounds__(512) void gemm256(const bf16* __restrict__ A,
                                               const bf16* __restrict__ Bt,
                                               const float* __restrict__ bias,
                                               void* __restrict__ outv, int M,
                                               int N, int K) {
  __shared__ __align__(16) bf16 sm[65536];  // 128 KiB: 2 x (A 32KB | B 32KB)
  const int tid = threadIdx.x;
  const int wave = tid >> 6;
  const int lane = tid & 63;
  const int nwg = gridDim.x;
  const int bid = blockIdx.x;
  const int swz = (bid & 7) * (nwg >> 3) + (bid >> 3);  // nwg % 8 == 0
  const int gn = N >> 8;
  const int bm0 = (swz / gn) << 8;
  const int bn0 = (swz % gn) << 8;
  const int wm64 = (wave >> 2) << 6;  // wave m-offset within half: 0 or 64
  const int wn32 = (wave & 3) << 5;   // wave n-offset within half: 0..96
  const int l31 = lane & 31;
  const int hi = lane >> 5;
  const int xorv = lane & 7;  // row&7 for all this lane's rows (blocks %8==0)

  // staging source: slot p -> row=p>>3, kc=(p&7)^(row&7)
  const int r0 = tid >> 3;
  const int kc0 = (tid & 7) ^ (r0 & 7);
  const bf16* Asrc = A + (size_t)(bm0 + r0) * K + kc0 * 8;
  const bf16* Bsrc = Bt + (size_t)(bn0 + r0) * K + kc0 * 8;
  const size_t rowK64 = (size_t)64 * K;
  const int NT = K >> 6;

  // 32-bit LDS read bases: byte = row*128 + (((ks<<1)^hi^xorv)<<4)
  // row = (mh*128|nh*128) + (wm64|wn32) + mb*32 + l31; literal adds mh/nh/mb.
  const unsigned smbase =
      (unsigned)(unsigned long long)(__attribute__((address_space(3)))
                                     bf16*)sm;
  const unsigned x = (unsigned)(hi ^ xorv);
  const unsigned aRow = (unsigned)((wm64 + l31) * 128);
  const unsigned bRow = (unsigned)((wn32 + l31) * 128);
  const unsigned a0k0 = smbase + aRow + (((0u << 1) ^ x) << 4);
  const unsigned a0k1 = smbase + aRow + (((1u << 1) ^ x) << 4);
  const unsigned a0k2 = smbase + aRow + (((2u << 1) ^ x) << 4);
  const unsigned a0k3 = smbase + aRow + (((3u << 1) ^ x) << 4);
  const unsigned b0k0 = smbase + 32768u + bRow + (((0u << 1) ^ x) << 4);
  const unsigned b0k1 = smbase + 32768u + bRow + (((1u << 1) ^ x) << 4);
  const unsigned b0k2 = smbase + 32768u + bRow + (((2u << 1) ^ x) << 4);
  const unsigned b0k3 = smbase + 32768u + bRow + (((3u << 1) ^ x) << 4);
  const unsigned a1k0 = a0k0 + 65536u, a1k1 = a0k1 + 65536u;
  const unsigned a1k2 = a0k2 + 65536u, a1k3 = a0k3 + 65536u;
  const unsigned b1k0 = b0k0 + 65536u, b1k1 = b0k1 + 65536u;
  const unsigned b1k2 = b0k2 + 65536u, b1k3 = b0k3 + 65536u;

  f32x16 acc[4][2];
#pragma unroll
  for (int i = 0; i < 4; ++i)
#pragma unroll
    for (int j = 0; j < 2; ++j)
#pragma unroll
      for (int r = 0; r < 16; ++r) acc[i][j][r] = 0.f;

  f32x4 AcR[2][4], BcR[2][4];

  // prologue FIFO: tile0 x4 halves, then {A(1,h0), B(1,h1)} (12 gloads)
  STG_A(0, 0, 0);
  STG_B(0, 0, 0);
  STG_A(0, 1, 0);
  STG_B(0, 1, 0);
  STG_A(1, 0, 1);
  STG_B(1, 1, 1);

  for (int t = 0; t < NT; t += 2) {
    TILE_BODY(t, 0, a0k0, a0k1, a0k2, a0k3, b0k0, b0k1, b0k2, b0k3);
    TILE_BODY(t + 1, 1, a1k0, a1k1, a1k2, a1k3, b1k0, b1k1, b1k2, b1k3);
  }

  // epilogue; 32x32 C/D: col = lane&31, row = (r&3) + 8*(r>>2) + 4*hi
#pragma unroll
  for (int mi = 0; mi < 4; ++mi) {
    int rowb = bm0 + (mi >> 1) * 128 + wm64 + (mi & 1) * 32 + 4 * hi;
#pragma unroll
    for (int nh = 0; nh < 2; ++nh) {
      int col = bn0 + nh * 128 + wn32 + l31;
      float bv = bias[col];
#pragma unroll
      for (int r = 0; r < 16; ++r) {
        int grow = rowb + (r & 3) + 8 * (r >> 2);
        size_t o = (size_t)grow * N + col;
        float v = acc[mi][nh][r] + bv;
        if (EPI == 0) {
          float g = 0.5f * v * (1.f + erff(v * 0.70710678118654752f));
          ((bf16*)outv)[o] = __float2bfloat16(g);
        } else {
          ((float*)outv)[o] = v;
        }
      }
    }
  }
}

extern "C" void kernel_launch(void* const* d_in, const int* in_sizes, int n_in,
                              void* d_out, int out_size, void* d_ws,
                              size_t ws_size, hipStream_t stream) {
  const int* idx = (const int*)d_in[0];       // [B,L]
  const float* Mlog = (const float*)d_in[1];  // [V,V]
  const float* W1 = (const float*)d_in[2];    // [V,2V]
  const float* b1 = (const float*)d_in[3];    // [2V]
  const float* W2 = (const float*)d_in[4];    // [2V,V]
  const float* b2 = (const float*)d_in[5];    // [V]
  float* out = (float*)d_out;                 // [B,L,V] f32

  char* ws = (char*)d_ws;
  const size_t MB64 = 64ull << 20;
  bf16* ctx = (bf16*)ws;             // 64 MiB  [8192][4096] (dead after GEMM1)
  bf16* W2t = (bf16*)ws;             // aliases ctx: [4096][8192]
  bf16* W1t = (bf16*)(ws + MB64);    // 64 MiB  [8192][4096]
  bf16* h = (bf16*)(ws + 2 * MB64);  // 128 MiB [8192][8192]
  float* segsum = (float*)h;         // 1 MiB, dead before GEMM1 writes h
  (void)ws_size;

  dim3 tb(32, 8);
  // W1^T cast
  transpose_f32_bf16<<<dim3(8192 / 32, 4096 / 32), tb, 0, stream>>>(W1, W1t,
                                                                    4096, 8192);
  // ctx = causal-mean(sigmoid(M)[idx]), segment-parallel two-pass
  ctx_partial<<<BB * 16 * SEG, 256, 0, stream>>>(idx, Mlog, segsum);
  ctx_final<<<BB * 16 * SEG, 256, 0, stream>>>(idx, Mlog, segsum, ctx);
  // h = gelu(ctx @ W1 + b1)  -> bf16
  gemm256<0><<<(8192 / 256) * (8192 / 256), 512, 0, stream>>>(
      ctx, W1t, b1, h, 8192, 8192, 4096);
  // W2^T cast (reuses ctx space)
  transpose_f32_bf16<<<dim3(4096 / 32, 8192 / 32), tb, 0, stream>>>(W2, W2t,
                                                                    8192, 4096);
  // out = h @ W2 + b2  -> f32
  gemm256<1><<<(8192 / 256) * (4096 / 256), 512, 0, stream>>>(
      h, W2t, b2, out, 8192, 4096, 8192);
}

// Round 13
// 987.710 us; speedup vs baseline: 3.6659x; 1.2283x over previous
//
#include <hip/hip_runtime.h>
#include <hip/hip_bf16.h>

#define VOCAB 4096
#define BB 4
#define LL 2048
#define SEG 16
#define SEGL 128  // LL/SEG

typedef __hip_bfloat16 bf16;
typedef __bf16 bf16x8 __attribute__((ext_vector_type(8)));
typedef float f32x4 __attribute__((ext_vector_type(4)));

__device__ __forceinline__ void gload16(const void* g, void* l) {
  __builtin_amdgcn_global_load_lds(
      (const __attribute__((address_space(1))) unsigned int*)g,
      (__attribute__((address_space(3))) unsigned int*)l, 16, 0, 0);
}

__device__ __forceinline__ bf16x8 as_bf(f32x4 v) {
  union { f32x4 f; bf16x8 b; } u;
  u.f = v;
  return u.b;
}

// ---------------- transpose f32 [K][N] -> bf16 [N][K] ----------------
__global__ void transpose_f32_bf16(const float* __restrict__ in,
                                   bf16* __restrict__ out, int K, int N) {
  __shared__ float tile[32][33];
  int bx = blockIdx.x;  // tile along N
  int by = blockIdx.y;  // tile along K
  int x = bx * 32 + threadIdx.x;
#pragma unroll
  for (int i = threadIdx.y; i < 32; i += 8)
    tile[i][threadIdx.x] = in[(size_t)(by * 32 + i) * N + x];
  __syncthreads();
  int k = by * 32 + threadIdx.x;
#pragma unroll
  for (int i = threadIdx.y; i < 32; i += 8)
    out[(size_t)(bx * 32 + i) * K + k] = __float2bfloat16(tile[threadIdx.x][i]);
}

// -------- ctx pass A: per-segment sigmoid column sums --------
__global__ void ctx_partial(const int* __restrict__ idx,
                            const float* __restrict__ Mlog,
                            float* __restrict__ segsum) {
  int b = blockIdx.x / (16 * SEG);
  int rem = blockIdx.x % (16 * SEG);
  int chunk = rem / SEG;
  int s = rem % SEG;
  int col = chunk * 256 + threadIdx.x;
  __shared__ int sidx[SEGL];
  if (threadIdx.x < SEGL)
    sidx[threadIdx.x] = idx[b * LL + s * SEGL + threadIdx.x];
  __syncthreads();
  const float* base = Mlog + col;
  float a0 = 0.f, a1 = 0.f, a2 = 0.f, a3 = 0.f;
#pragma unroll 4
  for (int t = 0; t < SEGL; t += 4) {
    float v0 = base[(size_t)sidx[t + 0] * VOCAB];
    float v1 = base[(size_t)sidx[t + 1] * VOCAB];
    float v2 = base[(size_t)sidx[t + 2] * VOCAB];
    float v3 = base[(size_t)sidx[t + 3] * VOCAB];
    a0 += 1.f / (1.f + __expf(-v0));
    a1 += 1.f / (1.f + __expf(-v1));
    a2 += 1.f / (1.f + __expf(-v2));
    a3 += 1.f / (1.f + __expf(-v3));
  }
  segsum[(size_t)blockIdx.x * 256 + threadIdx.x] = (a0 + a1) + (a2 + a3);
}

// -------- ctx pass B: replay segment with offset, write running mean --------
__global__ void ctx_final(const int* __restrict__ idx,
                          const float* __restrict__ Mlog,
                          const float* __restrict__ segsum,
                          bf16* __restrict__ ctx) {
  int b = blockIdx.x / (16 * SEG);
  int rem = blockIdx.x % (16 * SEG);
  int chunk = rem / SEG;
  int s = rem % SEG;
  int col = chunk * 256 + threadIdx.x;
  __shared__ int sidx[SEGL];
  if (threadIdx.x < SEGL)
    sidx[threadIdx.x] = idx[b * LL + s * SEGL + threadIdx.x];
  __syncthreads();
  const float* ss = segsum + (size_t)((b * 16 + chunk) * SEG) * 256 + threadIdx.x;
  float acc = 0.f;
  for (int s2 = 0; s2 < s; ++s2) acc += ss[(size_t)s2 * 256];
  const float* base = Mlog + col;
  bf16* outp = ctx + ((size_t)b * LL + (size_t)s * SEGL) * VOCAB + col;
#pragma unroll 8
  for (int t = 0; t < SEGL; ++t) {
    float v = base[(size_t)sidx[t] * VOCAB];
    acc += 1.f / (1.f + __expf(-v));
    float inv = __fdividef(1.f, (float)(s * SEGL + t + 1));
    outp[(size_t)t * VOCAB] = __float2bfloat16(acc * inv);
  }
}

// ------- 256x256 bf16 GEMM — r8 skeleton + B0-carry balanced phases -------
// (r12 design + LAST-TILE FIX). 512 thr (2x4 waves), BK=64, 128KiB LDS dbuf,
// r8's proven chunk-XOR layout (0 conflicts), asm ds_read_b128, 2 BAR/tile.
// Balanced {8,4,8,4} read phases; B0(t+1) is ds_read during t.ph4 from ~p
// and carried in regs across the tile boundary (bX/bY parity rotation).
// A staged one tile ahead (ph1/ph2 -> ~p), B two ahead (ph3/ph4 -> p).
// Waits (own-wave FIFO, re-traced t0/t1/steady/NT-2/NT-1):
//   top: VMW(4) drains {B(t,h1), A(t,h0), A(t,h1)}, keeps B(t+1,*) in
//        flight. *** r12 BUG: at t=NT-1 the B-stages were skipped so only
//        A(NT-1)'s own 4 loads are outstanding and VMW(4) was a NO-OP ->
//        ph1 raced the DMA (absmax 0.35 = one stale K-tile). Fix: VMW(0)
//        at the last tile. ***
//   mid: VMW(6) drains exactly B(t+1,h0) -> publishes it for ph4's
//        carry-read. WAR: B-h0(p) is NOT ds_read during t (the carry);
//        B-h1(p) drained pre-mid; A(~p) drained pre-top.
// EPI==0: out = bf16 gelu_exact(C)   EPI==1: out = f32 C

#define BAR() asm volatile("s_barrier" ::: "memory")
#define LGKM0() asm volatile("s_waitcnt lgkmcnt(0)" ::: "memory")
#define VMW(n_) asm volatile("s_waitcnt vmcnt(" #n_ ")" ::: "memory")
#define SB0() __builtin_amdgcn_sched_barrier(0)
#define P1() __builtin_amdgcn_s_setprio(1)
#define P0() __builtin_amdgcn_s_setprio(0)

#define STG_A(t_, h_, b_)                                           \
  {                                                                 \
    const bf16* s_ = Asrc + (size_t)(h_)*128 * K + (size_t)(t_)*64; \
    bf16* d_ = sm + (b_)*32768 + (h_)*8192 + wave * 512;            \
    gload16(s_, d_);                                                \
    gload16(s_ + rowK64, d_ + 4096);                                \
  }
#define STG_B(t_, h_, b_)                                           \
  {                                                                 \
    const bf16* s_ = Bsrc + (size_t)(h_)*128 * K + (size_t)(t_)*64; \
    bf16* d_ = sm + (b_)*32768 + 16384 + (h_)*8192 + wave * 512;    \
    gload16(s_, d_);                                                \
    gload16(s_ + rowK64, d_ + 4096);                                \
  }

// one asm LDS read: 16B into a f32x4, literal byte offset
#define RD1(dst_, base_, off_)                       \
  asm volatile("ds_read_b128 %0, %1 offset:%2"       \
               : "=v"(dst_)                          \
               : "v"(base_), "i"(off_)               \
               : "memory")

// A quadrant mh_: 8 reads (4 m-frags x 2 k-chunks) -> af
#define RD_A(b0_, b1_, mh_)                    \
  RD1(af[0][0], b0_, (mh_)*16384 + 0);         \
  RD1(af[0][1], b1_, (mh_)*16384 + 0);         \
  RD1(af[1][0], b0_, (mh_)*16384 + 2048);      \
  RD1(af[1][1], b1_, (mh_)*16384 + 2048);      \
  RD1(af[2][0], b0_, (mh_)*16384 + 4096);      \
  RD1(af[2][1], b1_, (mh_)*16384 + 4096);      \
  RD1(af[3][0], b0_, (mh_)*16384 + 6144);      \
  RD1(af[3][1], b1_, (mh_)*16384 + 6144);

// B quadrant nh_ into dst_: 4 reads
#define RD_B(dst_, b0_, b1_, nh_)              \
  RD1(dst_[0][0], b0_, (nh_)*16384 + 0);       \
  RD1(dst_[0][1], b1_, (nh_)*16384 + 0);       \
  RD1(dst_[1][0], b0_, (nh_)*16384 + 2048);    \
  RD1(dst_[1][1], b1_, (nh_)*16384 + 2048);

#define MQ(mh_, nh_, B_)                                                     \
  _Pragma("unroll") for (int i_ = 0; i_ < 4; ++i_)                           \
      _Pragma("unroll") for (int j_ = 0; j_ < 2; ++j_) {                     \
    f32x4& c_ = acc[(mh_)*4 + i_][(nh_)*2 + j_];                             \
    c_ = __builtin_amdgcn_mfma_f32_16x16x32_bf16(as_bf(af[i_][0]),           \
                                                 as_bf(B_[j_][0]), c_, 0, 0, \
                                                 0);                         \
    c_ = __builtin_amdgcn_mfma_f32_16x16x32_bf16(as_bf(af[i_][1]),           \
                                                 as_bf(B_[j_][1]), c_, 0, 0, \
                                                 0);                         \
  }

// One K-tile. p_: buffer (literal 0/1). aK/bK: ds-read bases of buf p.
// bn0_/bn1_: B bases of buf ~p (for the B0(t+1) carry-read).
// Bc_: slot holding carried B0(t). Bn_: slot for B1(t), then B0(t+1).
#define TILE_BODY(T_, p_, aK0_, aK1_, bK0_, bK1_, bn0_, bn1_, Bc_, Bn_) \
  {                                                                     \
    /* top: A(t) ready. Last tile: B-stages were skipped at t-1 so the  \
       queue holds only A(t)'s own 4 loads -> must drain fully. */      \
    if ((T_) + 1 < NT) { VMW(4); } else { VMW(0); }                     \
    BAR();                                                              \
    /* ph1: rd A0(8) ; stg A(t+1,h0)->~p ; MFMA (0,0)=A0 x Bc */        \
    RD_A(aK0_, aK1_, 0);                                                \
    if ((T_) + 1 < NT) STG_A((T_) + 1, 0, (p_) ^ 1);                    \
    LGKM0();                                                            \
    SB0();                                                              \
    P1(); MQ(0, 0, Bc_); P0();                                          \
    /* ph2: rd B1(4)->Bn ; stg A(t+1,h1)->~p ; MFMA (0,1)=A0 x Bn */    \
    RD_B(Bn_, bK0_, bK1_, 1);                                           \
    if ((T_) + 1 < NT) STG_A((T_) + 1, 1, (p_) ^ 1);                    \
    LGKM0();                                                            \
    SB0();                                                              \
    P1(); MQ(0, 1, Bn_); P0();                                          \
    /* mid: publish B(t+1,h0) (staged (t-1).ph3) */                     \
    VMW(6);                                                             \
    BAR();                                                              \
    /* ph3: rd A1(8) ; stg B(t+2,h0)->p ; MFMA (1,1)=A1 x Bn */         \
    RD_A(aK0_, aK1_, 1);                                                \
    if ((T_) + 2 < NT) STG_B((T_) + 2, 0, (p_));                        \
    LGKM0();                                                            \
    SB0();                                                              \
    P1(); MQ(1, 1, Bn_); P0();                                          \
    /* ph4: rd B0(t+1)(4) from ~p -> Bn (B1 dead) ; stg B(t+2,h1)->p ;  \
       MFMA (1,0)=A1 x Bc (no wait: A1 drained, Bc stable) */           \
    if ((T_) + 1 < NT) RD_B(Bn_, bn0_, bn1_, 0);                        \
    if ((T_) + 2 < NT) STG_B((T_) + 2, 1, (p_));                        \
    P1(); MQ(1, 0, Bc_); P0();                                          \
  }

template <int EPI>
__global__ __launch_bounds__(512) void gemm256(const bf16* __restrict__ A,
                                               const bf16* __restrict__ Bt,
                                               const float* __restrict__ bias,
                                               void* __restrict__ outv, int M,
                                               int N, int K) {
  __shared__ __align__(16) bf16 sm[65536];  // 128 KiB: 2 x (A 32KB | B 32KB)
  const int tid = threadIdx.x;
  const int wave = tid >> 6;
  const int lane = tid & 63;
  const int nwg = gridDim.x;
  const int bid = blockIdx.x;
  const int swz = (bid & 7) * (nwg >> 3) + (bid >> 3);  // nwg % 8 == 0
  const int gn = N >> 8;
  const int bm0 = (swz / gn) << 8;
  const int bn0 = (swz % gn) << 8;
  const int wm64 = (wave >> 2) << 6;  // wave m-offset within half: 0 or 64
  const int wn32 = (wave & 3) << 5;   // wave n-offset within half: 0..96
  const int rsel = lane & 15;
  const int ksel = lane >> 4;
  const int xorv = rsel & 7;

  // staging source: thread covers slots tid and tid+512 of each half-tile;
  // slot p -> row=p>>3, kc=(p&7)^(row&7)
  const int r0 = tid >> 3;
  const int kc0 = (tid & 7) ^ (r0 & 7);
  const bf16* Asrc = A + (size_t)(bm0 + r0) * K + kc0 * 8;
  const bf16* Bsrc = Bt + (size_t)(bn0 + r0) * K + kc0 * 8;
  const size_t rowK64 = (size_t)64 * K;
  const int NT = K >> 6;

  // 32-bit LDS byte bases for asm ds_read (chunk-XOR folded in)
  const unsigned smbase =
      (unsigned)(unsigned long long)(__attribute__((address_space(3)))
                                     bf16*)sm;
  const unsigned kT0 = (unsigned)((ksel ^ xorv) << 4);
  const unsigned kT1 = (unsigned)(((ksel + 4) ^ xorv) << 4);
  const unsigned aRow = (unsigned)((wm64 + rsel) * 128);
  const unsigned bRow = (unsigned)((wn32 + rsel) * 128);
  const unsigned a00 = smbase + aRow + kT0;
  const unsigned a10 = smbase + aRow + kT1;
  const unsigned b00 = smbase + 32768u + bRow + kT0;
  const unsigned b10 = smbase + 32768u + bRow + kT1;
  const unsigned a01 = a00 + 65536u, a11 = a10 + 65536u;
  const unsigned b01 = b00 + 65536u, b11 = b10 + 65536u;

  f32x4 acc[8][4];
#pragma unroll
  for (int i = 0; i < 8; ++i)
#pragma unroll
    for (int j = 0; j < 4; ++j) acc[i][j] = (f32x4){0.f, 0.f, 0.f, 0.f};

  f32x4 af[4][2], bX[2][2], bY[2][2];

  // prologue: A(0)->buf0, B(0)->buf0, B(1)->buf1 (12 gloads, FIFO order);
  // VMW(4) drains A(0)+B(0) (first 8), leaves B(1) in flight; then read the
  // initial carried B0(0) into bX (drained by t0.ph1's LGKM0).
  STG_A(0, 0, 0);
  STG_A(0, 1, 0);
  STG_B(0, 0, 0);
  STG_B(0, 1, 0);
  STG_B(1, 0, 1);
  STG_B(1, 1, 1);
  VMW(4);
  BAR();
  RD_B(bX, b00, b10, 0);

  for (int t = 0; t < NT; t += 2) {
    TILE_BODY(t, 0, a00, a10, b00, b10, b01, b11, bX, bY);
    TILE_BODY(t + 1, 1, a01, a11, b01, b11, b00, b10, bY, bX);
  }

  // epilogue; C/D layout: col = lane&15, row = (lane>>4)*4 + reg
  const int cl = lane & 15;
  const int rg = lane >> 4;
#pragma unroll
  for (int m = 0; m < 8; ++m) {
    int grow = bm0 + ((m >> 2) << 7) + wm64 + ((m & 3) << 4) + rg * 4;
#pragma unroll
    for (int n = 0; n < 4; ++n) {
      int col = bn0 + ((n >> 1) << 7) + wn32 + ((n & 1) << 4) + cl;
      float bv = bias[col];
#pragma unroll
      for (int r = 0; r < 4; ++r) {
        size_t o = (size_t)(grow + r) * N + col;
        float v = acc[m][n][r] + bv;
        if (EPI == 0) {
          float g = 0.5f * v * (1.f + erff(v * 0.70710678118654752f));
          ((bf16*)outv)[o] = __float2bfloat16(g);
        } else {
          ((float*)outv)[o] = v;
        }
      }
    }
  }
}

extern "C" void kernel_launch(void* const* d_in, const int* in_sizes, int n_in,
                              void* d_out, int out_size, void* d_ws,
                              size_t ws_size, hipStream_t stream) {
  const int* idx = (const int*)d_in[0];       // [B,L]
  const float* Mlog = (const float*)d_in[1];  // [V,V]
  const float* W1 = (const float*)d_in[2];    // [V,2V]
  const float* b1 = (const float*)d_in[3];    // [2V]
  const float* W2 = (const float*)d_in[4];    // [2V,V]
  const float* b2 = (const float*)d_in[5];    // [V]
  float* out = (float*)d_out;                 // [B,L,V] f32

  char* ws = (char*)d_ws;
  const size_t MB64 = 64ull << 20;
  bf16* ctx = (bf16*)ws;             // 64 MiB  [8192][4096] (dead after GEMM1)
  bf16* W2t = (bf16*)ws;             // aliases ctx: [4096][8192]
  bf16* W1t = (bf16*)(ws + MB64);    // 64 MiB  [8192][4096]
  bf16* h = (bf16*)(ws + 2 * MB64);  // 128 MiB [8192][8192]
  float* segsum = (float*)h;         // 1 MiB, dead before GEMM1 writes h
  (void)ws_size;

  dim3 tb(32, 8);
  // W1^T cast
  transpose_f32_bf16<<<dim3(8192 / 32, 4096 / 32), tb, 0, stream>>>(W1, W1t,
                                                                    4096, 8192);
  // ctx = causal-mean(sigmoid(M)[idx]), segment-parallel two-pass
  ctx_partial<<<BB * 16 * SEG, 256, 0, stream>>>(idx, Mlog, segsum);
  ctx_final<<<BB * 16 * SEG, 256, 0, stream>>>(idx, Mlog, segsum, ctx);
  // h = gelu(ctx @ W1 + b1)  -> bf16
  gemm256<0><<<(8192 / 256) * (8192 / 256), 512, 0, stream>>>(
      ctx, W1t, b1, h, 8192, 8192, 4096);
  // W2^T cast (reuses ctx space)
  transpose_f32_bf16<<<dim3(4096 / 32, 8192 / 32), tb, 0, stream>>>(W2, W2t,
                                                                    8192, 4096);
  // out = h @ W2 + b2  -> f32
  gemm256<1><<<(8192 / 256) * (4096 / 256), 512, 0, stream>>>(
      h, W2t, b2, out, 8192, 4096, 8192);
}